// Round 2
// baseline (1945.788 us; speedup 1.0000x reference)
//
#include <hip/hip_runtime.h>

// ---------------------------------------------------------------------------
// GDN attention block, MI355X (gfx950).
//   1. cast x -> bf16
//   2. transpose weights -> bf16 B^T packs
//   3. bf16 MFMA GEMM (128x128 tile, global_load_lds w16), bf16 outputs:
//      xqkv = x@[Wq Wk Wv]  (bf16), rqk = x@[Wrq Wrk] (bf16)
//   4. fl: alpha/beta = sigmoid(x@Wf+bf / x@Wl+bl)
//   5. prep: causal dwconv(K=4) + head rmsnorm + low-rank mix + k-tilde norm
//      -> qt,kt,vc bf16 [BH][S][64]
//   6. scan: gated delta rule. 2 blocks per (b,h) (32 rows each), 8 lanes/row.
//      Chunked (32 steps) LDS staging, double-buffered, async reg prefetch
//      (T14: loads for chunk c+1 in flight across barriers during compute c).
//   7. rmsnorm over D=1024 -> bf16
//   8. GEMM @ Wo -> d_out f32
// Workspace: ~148 MiB peak (attn aliases xqkv, normed aliases rqk).
// ---------------------------------------------------------------------------

typedef __attribute__((ext_vector_type(8))) short short8;
typedef __attribute__((ext_vector_type(4))) float f32x4;

#define B_ 2
#define S_ 4096
#define D_ 1024
#define H_ 16
#define R_ 48
#define M_ 8192  // B*S
#define CHUNK 32

__device__ __forceinline__ unsigned short f2bf(float f) {
  unsigned u = __float_as_uint(f);
  u += 0x7FFFu + ((u >> 16) & 1u);
  return (unsigned short)(u >> 16);
}
__device__ __forceinline__ float bf2f(unsigned short u) {
  return __uint_as_float(((unsigned)u) << 16);
}

#define GLDS16(g, l) __builtin_amdgcn_global_load_lds(                        \
    (const __attribute__((address_space(1))) unsigned int*)(g),              \
    (__attribute__((address_space(3))) unsigned int*)(l), 16, 0, 0)

// --------------------------------------------------------------- cast x->bf16
__global__ __launch_bounds__(256) void cast_bf16_kernel(
    const float* __restrict__ in, unsigned short* __restrict__ out, int n4) {
  int i = blockIdx.x * 256 + threadIdx.x;
  for (; i < n4; i += gridDim.x * 256) {
    float4 v = ((const float4*)in)[i];
    ushort4 o;
    o.x = f2bf(v.x); o.y = f2bf(v.y); o.z = f2bf(v.z); o.w = f2bf(v.w);
    ((ushort4*)out)[i] = o;
  }
}

// ------------------------------------------------- W[K][N] -> Wt[N][K] (bf16)
__global__ void transpose_w_kernel(const float* __restrict__ W,
                                   unsigned short* __restrict__ Wt,
                                   int Kd, int N) {
  __shared__ float tile[32][33];
  int n0 = blockIdx.x * 32, k0 = blockIdx.y * 32;
  int tx = threadIdx.x, ty = threadIdx.y;  // 32 x 8
#pragma unroll
  for (int i = 0; i < 32; i += 8)
    tile[ty + i][tx] = W[(size_t)(k0 + ty + i) * N + n0 + tx];
  __syncthreads();
#pragma unroll
  for (int i = 0; i < 32; i += 8)
    Wt[(size_t)(n0 + ty + i) * Kd + k0 + tx] = f2bf(tile[tx][ty + i]);
}

// ------------------------------------------------------------- bf16 MFMA GEMM
// C[M,N] = A[M,K]bf16 @ Bt[N,K]bf16^T.  128x128 tile, BK=64, 4 waves.
template <bool BF16OUT>
__global__ __launch_bounds__(256) void gemm_bt_kernel(
    const unsigned short* __restrict__ A, const unsigned short* __restrict__ Bt,
    void* __restrict__ Cv, int M, int N, int Kd) {
  __shared__ alignas(16) unsigned short lds[2 * 128 * 64];  // 32 KiB
  unsigned short* ldsA = lds;
  unsigned short* ldsB = lds + 128 * 64;
  int tid = threadIdx.x;
  int wave = tid >> 6, lane = tid & 63;
  int nBlocks = N >> 7;
  int bm = blockIdx.x / nBlocks, bn = blockIdx.x % nBlocks;
  int m0 = bm << 7, n0 = bn << 7;
  int wm = (wave >> 1) << 6, wn = (wave & 1) << 6;

  f32x4 acc[4][4] = {};

  int rowInChunk = lane >> 3;  // 8 rows per 1KiB chunk (128B rows)
  int kOff = (lane & 7) * 8;   // 16B per lane

  const unsigned short* Abase = A + (size_t)m0 * Kd;
  const unsigned short* Bbase = Bt + (size_t)n0 * Kd;

  for (int k0 = 0; k0 < Kd; k0 += 64) {
    __syncthreads();
#pragma unroll
    for (int r = 0; r < 4; r++) {
      int c = wave * 4 + r;
      int row = c * 8 + rowInChunk;
      GLDS16(Abase + (size_t)row * Kd + k0 + kOff, ldsA + c * 512);
    }
#pragma unroll
    for (int r = 0; r < 4; r++) {
      int c = wave * 4 + r;
      int row = c * 8 + rowInChunk;
      GLDS16(Bbase + (size_t)row * Kd + k0 + kOff, ldsB + c * 512);
    }
    asm volatile("s_waitcnt vmcnt(0)" ::: "memory");
    __syncthreads();
#pragma unroll
    for (int kk = 0; kk < 2; kk++) {
      short8 af[4], bfr[4];
      int kb = kk * 32 + (lane >> 4) * 8;
#pragma unroll
      for (int i = 0; i < 4; i++) {
        int ar = wm + i * 16 + (lane & 15);
        af[i] = *(const short8*)(ldsA + ar * 64 + kb);
        int br = wn + i * 16 + (lane & 15);
        bfr[i] = *(const short8*)(ldsB + br * 64 + kb);
      }
#pragma unroll
      for (int i = 0; i < 4; i++)
#pragma unroll
        for (int j = 0; j < 4; j++)
          acc[i][j] = __builtin_amdgcn_mfma_f32_16x16x32_bf16(
              af[i], bfr[j], acc[i][j], 0, 0, 0);
    }
  }
  int cr = (lane >> 4) * 4;
  int cc = lane & 15;
#pragma unroll
  for (int i = 0; i < 4; i++)
#pragma unroll
    for (int j = 0; j < 4; j++)
#pragma unroll
      for (int rg = 0; rg < 4; rg++) {
        int row = m0 + wm + i * 16 + cr + rg;
        int col = n0 + wn + j * 16 + cc;
        if (BF16OUT)
          ((unsigned short*)Cv)[(size_t)row * N + col] = f2bf(acc[i][j][rg]);
        else
          ((float*)Cv)[(size_t)row * N + col] = acc[i][j][rg];
      }
}

// ------------------------------------------------- alpha/beta gate projection
__global__ __launch_bounds__(256) void fl_kernel(
    const float* __restrict__ x, const float* __restrict__ Wf,
    const float* __restrict__ bfv, const float* __restrict__ Wl,
    const float* __restrict__ blv, float* __restrict__ alpha,
    float* __restrict__ beta) {
  __shared__ float xs[1024];
  int m = blockIdx.x;
  int b = m >> 12, t = m & 4095;
  int tid = threadIdx.x;
  *(float4*)(xs + tid * 4) = *(const float4*)(x + (size_t)m * 1024 + tid * 4);
  __syncthreads();
  int out = tid >> 3, part = tid & 7;
  const float* W = (out < 16) ? Wf : Wl;
  int h = out & 15;
  float acc = 0.f;
  int k0 = part * 128;
#pragma unroll 4
  for (int kk = k0; kk < k0 + 128; kk++) acc = fmaf(xs[kk], W[kk * 16 + h], acc);
  acc += __shfl_xor(acc, 1);
  acc += __shfl_xor(acc, 2);
  acc += __shfl_xor(acc, 4);
  if (part == 0) {
    float bias = (out < 16) ? bfv[h] : blv[h];
    float z = acc + bias;
    float s = 1.f / (1.f + __expf(-z));
    float* dst = (out < 16) ? alpha : beta;
    dst[((size_t)(b * 16 + h)) * 4096 + t] = s;
  }
}

// ------------------------ conv + rmsnorm + low-rank mix + k-tilde normalize
__global__ __launch_bounds__(256) void prep_kernel(
    const unsigned short* __restrict__ xqkv, const unsigned short* __restrict__ rqk,
    const float* __restrict__ cq, const float* __restrict__ ck,
    const float* __restrict__ cv, const float* __restrict__ gs,
    const float* __restrict__ qnw, const float* __restrict__ knw,
    unsigned short* __restrict__ qt, unsigned short* __restrict__ kt,
    unsigned short* __restrict__ vc) {
  int m = blockIdx.x;
  int b = m >> 12, t = m & 4095;
  int tid = threadIdx.x;
  int c4 = tid << 2;  // channel base
  int h = c4 >> 6;    // head
  int j4 = c4 & 63;   // within-head channel base

  float wq[4][4], wk[4][4], wv[4][4];
#pragma unroll
  for (int u = 0; u < 4; u++) {
    *(float4*)wq[u] = *(const float4*)(cq + (c4 + u) * 4);
    *(float4*)wk[u] = *(const float4*)(ck + (c4 + u) * 4);
    *(float4*)wv[u] = *(const float4*)(cv + (c4 + u) * 4);
  }
  float qv[4] = {0, 0, 0, 0}, kv[4] = {0, 0, 0, 0}, vv[4] = {0, 0, 0, 0};
#pragma unroll
  for (int j = 0; j < 4; j++) {
    int tt = t + j - 3;
    if (tt < 0) continue;
    const unsigned short* xr = xqkv + ((size_t)((b << 12) + tt)) * 3072;
    ushort4 uq = *(const ushort4*)(xr + c4);
    ushort4 uk = *(const ushort4*)(xr + 1024 + c4);
    ushort4 uv = *(const ushort4*)(xr + 2048 + c4);
    float xq[4] = {bf2f(uq.x), bf2f(uq.y), bf2f(uq.z), bf2f(uq.w)};
    float xk[4] = {bf2f(uk.x), bf2f(uk.y), bf2f(uk.z), bf2f(uk.w)};
    float xv[4] = {bf2f(uv.x), bf2f(uv.y), bf2f(uv.z), bf2f(uv.w)};
#pragma unroll
    for (int u = 0; u < 4; u++) {
      qv[u] = fmaf(wq[u][j], xq[u], qv[u]);
      kv[u] = fmaf(wk[u][j], xk[u], kv[u]);
      vv[u] = fmaf(wv[u][j], xv[u], vv[u]);
    }
  }
  // rmsnorm over head dim (16 lanes x 4 channels)
  float ssq = qv[0] * qv[0] + qv[1] * qv[1] + qv[2] * qv[2] + qv[3] * qv[3];
  ssq += __shfl_xor(ssq, 1); ssq += __shfl_xor(ssq, 2);
  ssq += __shfl_xor(ssq, 4); ssq += __shfl_xor(ssq, 8);
  float qsc = rsqrtf(ssq * (1.f / 64.f) + 1e-6f);
  float ssk = kv[0] * kv[0] + kv[1] * kv[1] + kv[2] * kv[2] + kv[3] * kv[3];
  ssk += __shfl_xor(ssk, 1); ssk += __shfl_xor(ssk, 2);
  ssk += __shfl_xor(ssk, 4); ssk += __shfl_xor(ssk, 8);
  float ksc = rsqrtf(ssk * (1.f / 64.f) + 1e-6f);

  float lam = fabsf(gs[h]);
  float rq[4] = {0, 0, 0, 0}, rk[4] = {0, 0, 0, 0};
  if (j4 < R_) {
    const unsigned short* rr = rqk + (size_t)m * 1536;
    ushort4 uq = *(const ushort4*)(rr + h * R_ + j4);
    ushort4 uk = *(const ushort4*)(rr + 768 + h * R_ + j4);
    rq[0] = bf2f(uq.x); rq[1] = bf2f(uq.y); rq[2] = bf2f(uq.z); rq[3] = bf2f(uq.w);
    rk[0] = bf2f(uk.x); rk[1] = bf2f(uk.y); rk[2] = bf2f(uk.z); rk[3] = bf2f(uk.w);
  }
  float qtv[4], ksum[4];
#pragma unroll
  for (int u = 0; u < 4; u++) {
    float qn = qv[u] * qsc * qnw[j4 + u];
    float kn = kv[u] * ksc * knw[j4 + u];
    qtv[u] = fmaf(lam, rq[u], qn);
    ksum[u] = fmaf(lam, rk[u], kn);
  }
  float ss2 = ksum[0] * ksum[0] + ksum[1] * ksum[1] + ksum[2] * ksum[2] +
              ksum[3] * ksum[3];
  ss2 += __shfl_xor(ss2, 1); ss2 += __shfl_xor(ss2, 2);
  ss2 += __shfl_xor(ss2, 4); ss2 += __shfl_xor(ss2, 8);
  float inv = 1.f / fmaxf(sqrtf(ss2), 1e-12f);

  size_t ob = ((size_t)((b * 16 + h) * 4096 + t)) * 64 + j4;
  ushort4 oq, ok, ov;
  oq.x = f2bf(qtv[0]); oq.y = f2bf(qtv[1]); oq.z = f2bf(qtv[2]); oq.w = f2bf(qtv[3]);
  ok.x = f2bf(ksum[0] * inv); ok.y = f2bf(ksum[1] * inv);
  ok.z = f2bf(ksum[2] * inv); ok.w = f2bf(ksum[3] * inv);
  ov.x = f2bf(vv[0]); ov.y = f2bf(vv[1]); ov.z = f2bf(vv[2]); ov.w = f2bf(vv[3]);
  *(ushort4*)(qt + ob) = oq;
  *(ushort4*)(kt + ob) = ok;
  *(ushort4*)(vc + ob) = ov;
}

// -------------------------------------------------------- gated delta scan
// 2 blocks per (b,h): rows rh*32..+31. thread (r=tid>>3, cg=tid&7) owns
// mem[r][cg*8..+8]. Chunked LDS staging (f32), double-buffered, async
// reg prefetch of next chunk in flight during compute (T14).
__global__ __launch_bounds__(256) void scan_kernel(
    const unsigned short* __restrict__ qt, const unsigned short* __restrict__ kt,
    const unsigned short* __restrict__ vc, const float* __restrict__ al,
    const float* __restrict__ be, float* __restrict__ attn) {
  __shared__ alignas(16) float sk[2][CHUNK][64];
  __shared__ alignas(16) float sq[2][CHUNK][64];
  __shared__ alignas(16) float sv[2][CHUNK][64];
  __shared__ float sab[2][64];  // [buf][0..31]=alpha, [32..63]=beta

  int bid = blockIdx.x;
  int bh = bid >> 1, rh = bid & 1;
  int b = bh >> 4, h = bh & 15;
  int tid = threadIdx.x;
  int r = rh * 32 + (tid >> 3);
  int cg = tid & 7;

  const unsigned short* kb = kt + (size_t)bh * S_ * 64;
  const unsigned short* qb = qt + (size_t)bh * S_ * 64;
  const unsigned short* vb = vc + (size_t)bh * S_ * 64;
  const float* ap = al + (size_t)bh * S_;
  const float* bp = be + (size_t)bh * S_;
  float* op = attn + (size_t)(b * S_) * 1024 + h * 64 + r;

  float mem[8];
#pragma unroll
  for (int i = 0; i < 8; i++) mem[i] = 0.f;

  // prologue: issue chunk-0 loads into regs
  short8 rk = *(const short8*)(kb + tid * 8);
  short8 rq = *(const short8*)(qb + tid * 8);
  short8 rv = *(const short8*)(vb + tid * 8);
  float rab = 0.f;
  if (tid < 64) rab = (tid < 32) ? ap[tid] : bp[tid - 32];

  const int nc = S_ / CHUNK;
  for (int c = 0; c < nc; ++c) {
    int p = c & 1;
    __syncthreads();  // buf[p] consumers (chunk c-2) done
    {                 // regs -> LDS (compiler inserts the vmcnt wait)
      float* dk = &sk[p][0][0] + tid * 8;
      float* dq = &sq[p][0][0] + tid * 8;
      float* dv = &sv[p][0][0] + tid * 8;
      f32x4 t0, t1;
#pragma unroll
      for (int u = 0; u < 4; u++) { t0[u] = bf2f((unsigned short)rk[u]); t1[u] = bf2f((unsigned short)rk[4 + u]); }
      *(f32x4*)dk = t0; *(f32x4*)(dk + 4) = t1;
#pragma unroll
      for (int u = 0; u < 4; u++) { t0[u] = bf2f((unsigned short)rq[u]); t1[u] = bf2f((unsigned short)rq[4 + u]); }
      *(f32x4*)dq = t0; *(f32x4*)(dq + 4) = t1;
#pragma unroll
      for (int u = 0; u < 4; u++) { t0[u] = bf2f((unsigned short)rv[u]); t1[u] = bf2f((unsigned short)rv[4 + u]); }
      *(f32x4*)dv = t0; *(f32x4*)(dv + 4) = t1;
      if (tid < 64) sab[p][tid] = rab;
    }
    if (c + 1 < nc) {  // issue next-chunk loads; stay in flight across barrier
      size_t off = (size_t)(c + 1) * (CHUNK * 64) + tid * 8;
      rk = *(const short8*)(kb + off);
      rq = *(const short8*)(qb + off);
      rv = *(const short8*)(vb + off);
      int t0g = (c + 1) * CHUNK;
      if (tid < 64) rab = (tid < 32) ? ap[t0g + tid] : bp[t0g + tid - 32];
    }
    __syncthreads();  // buf[p] ready
    int tg0 = c * CHUNK;
#pragma unroll 4
    for (int t = 0; t < CHUNK; t++) {
      f32x4 k0 = *(const f32x4*)&sk[p][t][cg * 8];
      f32x4 k1 = *(const f32x4*)&sk[p][t][cg * 8 + 4];
      f32x4 q0 = *(const f32x4*)&sq[p][t][cg * 8];
      f32x4 q1 = *(const f32x4*)&sq[p][t][cg * 8 + 4];
      float v = sv[p][t][r];
      float a = sab[p][t], bg = sab[p][32 + t];
      float pa = 0.f, pb = 0.f;
#pragma unroll
      for (int i = 0; i < 4; i++) {
        pa = fmaf(mem[i], k0[i], pa);
        pb = fmaf(mem[4 + i], k1[i], pb);
      }
      float pp = pa + pb;
      pp += __shfl_xor(pp, 1);
      pp += __shfl_xor(pp, 2);
      pp += __shfl_xor(pp, 4);
      float bd = bg * (v - pp);
      float oa = 0.f, ob = 0.f;
#pragma unroll
      for (int i = 0; i < 4; i++) {
        mem[i] = fmaf(a, mem[i], bd * k0[i]);
        mem[4 + i] = fmaf(a, mem[4 + i], bd * k1[i]);
        oa = fmaf(mem[i], q0[i], oa);
        ob = fmaf(mem[4 + i], q1[i], ob);
      }
      float o = oa + ob;
      o += __shfl_xor(o, 1);
      o += __shfl_xor(o, 2);
      o += __shfl_xor(o, 4);
      if (cg == 0) op[(size_t)(tg0 + t) * 1024] = o;
    }
  }
}

// ------------------------------------------------ output rmsnorm -> bf16 rows
__global__ __launch_bounds__(256) void rmsnorm_out_kernel(
    const float* __restrict__ attn, const float* __restrict__ onw,
    unsigned short* __restrict__ normed) {
  int m = blockIdx.x, tid = threadIdx.x;
  const float* row = attn + (size_t)m * 1024;
  float xv[4];
  *(float4*)xv = *(const float4*)(row + tid * 4);
  float ss = xv[0] * xv[0] + xv[1] * xv[1] + xv[2] * xv[2] + xv[3] * xv[3];
#pragma unroll
  for (int o = 1; o < 64; o <<= 1) ss += __shfl_xor(ss, o);
  __shared__ float wss[4];
  if ((tid & 63) == 0) wss[tid >> 6] = ss;
  __syncthreads();
  float tot = wss[0] + wss[1] + wss[2] + wss[3];
  float sc = rsqrtf(tot * (1.f / 1024.f) + 1e-6f);
  float wv[4];
  *(float4*)wv = *(const float4*)(onw + tid * 4);
  ushort4 o4;
  o4.x = f2bf(xv[0] * sc * wv[0]);
  o4.y = f2bf(xv[1] * sc * wv[1]);
  o4.z = f2bf(xv[2] * sc * wv[2]);
  o4.w = f2bf(xv[3] * sc * wv[3]);
  *(ushort4*)(normed + (size_t)m * 1024 + tid * 4) = o4;
}

// ---------------------------------------------------------------------------
extern "C" void kernel_launch(void* const* d_in, const int* in_sizes, int n_in,
                              void* d_out, int out_size, void* d_ws,
                              size_t ws_size, hipStream_t stream) {
  const float* x = (const float*)d_in[0];
  const float* Wq = (const float*)d_in[1];
  const float* Wk = (const float*)d_in[2];
  const float* Wv = (const float*)d_in[3];
  const float* Wo = (const float*)d_in[4];
  const float* conv_q = (const float*)d_in[5];
  const float* conv_k = (const float*)d_in[6];
  const float* conv_v = (const float*)d_in[7];
  const float* Wf = (const float*)d_in[8];
  const float* bfv = (const float*)d_in[9];
  const float* Wl = (const float*)d_in[10];
  const float* blv = (const float*)d_in[11];
  const float* gs = (const float*)d_in[14];
  const float* qn_w = (const float*)d_in[15];
  const float* kn_w = (const float*)d_in[16];
  const float* on_w = (const float*)d_in[17];

  char* ws = (char*)d_ws;
  size_t used = 0;
  auto alloc = [&](size_t bytes) -> void* {
    void* p = (void*)(ws + used);
    used += (bytes + 255) & ~(size_t)255;
    return p;
  };
  unsigned short* xb = (unsigned short*)alloc((size_t)M_ * D_ * 2);          // 16M
  unsigned short* wqkv_t = (unsigned short*)alloc((size_t)3072 * 1024 * 2);  // 6M
  unsigned short* wr_t = (unsigned short*)alloc((size_t)1536 * 1024 * 2);    // 3M
  unsigned short* wo_t = (unsigned short*)alloc((size_t)1024 * 1024 * 2);    // 2M
  unsigned short* xqkv = (unsigned short*)alloc((size_t)M_ * 3072 * 2);      // 48M
  unsigned short* rqk = (unsigned short*)alloc((size_t)M_ * 1536 * 2);       // 24M
  unsigned short* qt = (unsigned short*)alloc((size_t)M_ * 1024 * 2);        // 16M
  unsigned short* kt = (unsigned short*)alloc((size_t)M_ * 1024 * 2);        // 16M
  unsigned short* vc = (unsigned short*)alloc((size_t)M_ * 1024 * 2);        // 16M
  float* alpha = (float*)alloc((size_t)B_ * H_ * S_ * 4);
  float* beta = (float*)alloc((size_t)B_ * H_ * S_ * 4);
  // aliases onto dead buffers:
  float* attn = (float*)xqkv;            // 32M f32 into 48M region (xqkv dead)
  unsigned short* normed = rqk;          // 16M bf16 into 24M region (rqk dead)

  if (used > ws_size) return;  // diagnostic: absmax-fail (zero out) => ws too small

  cast_bf16_kernel<<<2048, 256, 0, stream>>>(x, xb, M_ * D_ / 4);

  dim3 tb(32, 8);
  transpose_w_kernel<<<dim3(32, 32), tb, 0, stream>>>(Wq, wqkv_t, 1024, 1024);
  transpose_w_kernel<<<dim3(32, 32), tb, 0, stream>>>(
      Wk, wqkv_t + (size_t)1024 * 1024, 1024, 1024);
  transpose_w_kernel<<<dim3(32, 32), tb, 0, stream>>>(
      Wv, wqkv_t + (size_t)2048 * 1024, 1024, 1024);
  transpose_w_kernel<<<dim3(24, 32), tb, 0, stream>>>(
      (const float*)d_in[12], wr_t, 1024, 768);
  transpose_w_kernel<<<dim3(24, 32), tb, 0, stream>>>(
      (const float*)d_in[13], wr_t + (size_t)768 * 1024, 1024, 768);
  transpose_w_kernel<<<dim3(32, 32), tb, 0, stream>>>(Wo, wo_t, 1024, 1024);

  gemm_bt_kernel<true><<<64 * 24, 256, 0, stream>>>(xb, wqkv_t, xqkv, M_, 3072, 1024);
  gemm_bt_kernel<true><<<64 * 12, 256, 0, stream>>>(xb, wr_t, rqk, M_, 1536, 1024);

  fl_kernel<<<M_, 256, 0, stream>>>(x, Wf, bfv, Wl, blv, alpha, beta);

  prep_kernel<<<M_, 256, 0, stream>>>(xqkv, rqk, conv_q, conv_k, conv_v, gs,
                                      qn_w, kn_w, qt, kt, vc);

  scan_kernel<<<B_ * H_ * 2, 256, 0, stream>>>(qt, kt, vc, alpha, beta, attn);

  rmsnorm_out_kernel<<<M_, 256, 0, stream>>>(attn, on_w, normed);

  gemm_bt_kernel<false><<<64 * 8, 256, 0, stream>>>(normed, wo_t, (float*)d_out,
                                                    M_, 1024, 1024);
}

// Round 3
// 1427.369 us; speedup vs baseline: 1.3632x; 1.3632x over previous
//
#include <hip/hip_runtime.h>

// ---------------------------------------------------------------------------
// GDN attention block, MI355X (gfx950).
//   1. cast x -> bf16
//   2. transpose weights -> bf16 B^T packs
//   3. bf16 MFMA GEMM (128x128 tile, global_load_lds w16), bf16 outputs
//   4. fl: alpha/beta gates
//   5. prep: causal dwconv(K=4) + head rmsnorm + low-rank mix + k-tilde norm
//   6. scan: gated delta rule. 8 blocks per (b,h) (8 rows x 8 lanes = 1 wave).
//      Row-reduce = 2 DPP quad_perm adds + 1 ds_swizzle (xor4) -- no
//      ds_bpermute chain. Chunked double-buffered LDS staging + reg prefetch.
//   7. rmsnorm over D=1024 -> bf16
//   8. GEMM @ Wo -> d_out f32
// ---------------------------------------------------------------------------

typedef __attribute__((ext_vector_type(8))) short short8;
typedef __attribute__((ext_vector_type(4))) float f32x4;

#define B_ 2
#define S_ 4096
#define D_ 1024
#define H_ 16
#define R_ 48
#define M_ 8192  // B*S
#define CHUNK 32

__device__ __forceinline__ unsigned short f2bf(float f) {
  unsigned u = __float_as_uint(f);
  u += 0x7FFFu + ((u >> 16) & 1u);
  return (unsigned short)(u >> 16);
}
__device__ __forceinline__ float bf2f(unsigned short u) {
  return __uint_as_float(((unsigned)u) << 16);
}

// sum over aligned 8-lane group: xor1,xor2 via DPP quad_perm (VALU), xor4 via
// ds_swizzle. All 8 lanes end with the group sum.
__device__ __forceinline__ float rowsum8(float x) {
  float y = x + __int_as_float(__builtin_amdgcn_update_dpp(
                    0, __float_as_int(x), 0xB1, 0xF, 0xF, true));  // [1,0,3,2]
  y = y + __int_as_float(__builtin_amdgcn_update_dpp(
              0, __float_as_int(y), 0x4E, 0xF, 0xF, true));        // [2,3,0,1]
  y = y + __int_as_float(
              __builtin_amdgcn_ds_swizzle(__float_as_int(y), 0x101F));  // ^4
  return y;
}

#define GLDS16(g, l) __builtin_amdgcn_global_load_lds(                        \
    (const __attribute__((address_space(1))) unsigned int*)(g),              \
    (__attribute__((address_space(3))) unsigned int*)(l), 16, 0, 0)

// --------------------------------------------------------------- cast x->bf16
__global__ __launch_bounds__(256) void cast_bf16_kernel(
    const float* __restrict__ in, unsigned short* __restrict__ out, int n4) {
  int i = blockIdx.x * 256 + threadIdx.x;
  for (; i < n4; i += gridDim.x * 256) {
    float4 v = ((const float4*)in)[i];
    ushort4 o;
    o.x = f2bf(v.x); o.y = f2bf(v.y); o.z = f2bf(v.z); o.w = f2bf(v.w);
    ((ushort4*)out)[i] = o;
  }
}

// ------------------------------------------------- W[K][N] -> Wt[N][K] (bf16)
__global__ void transpose_w_kernel(const float* __restrict__ W,
                                   unsigned short* __restrict__ Wt,
                                   int Kd, int N) {
  __shared__ float tile[32][33];
  int n0 = blockIdx.x * 32, k0 = blockIdx.y * 32;
  int tx = threadIdx.x, ty = threadIdx.y;  // 32 x 8
#pragma unroll
  for (int i = 0; i < 32; i += 8)
    tile[ty + i][tx] = W[(size_t)(k0 + ty + i) * N + n0 + tx];
  __syncthreads();
#pragma unroll
  for (int i = 0; i < 32; i += 8)
    Wt[(size_t)(n0 + ty + i) * Kd + k0 + tx] = f2bf(tile[tx][ty + i]);
}

// ------------------------------------------------------------- bf16 MFMA GEMM
template <bool BF16OUT>
__global__ __launch_bounds__(256) void gemm_bt_kernel(
    const unsigned short* __restrict__ A, const unsigned short* __restrict__ Bt,
    void* __restrict__ Cv, int M, int N, int Kd) {
  __shared__ alignas(16) unsigned short lds[2 * 128 * 64];  // 32 KiB
  unsigned short* ldsA = lds;
  unsigned short* ldsB = lds + 128 * 64;
  int tid = threadIdx.x;
  int wave = tid >> 6, lane = tid & 63;
  int nBlocks = N >> 7;
  int bm = blockIdx.x / nBlocks, bn = blockIdx.x % nBlocks;
  int m0 = bm << 7, n0 = bn << 7;
  int wm = (wave >> 1) << 6, wn = (wave & 1) << 6;

  f32x4 acc[4][4] = {};

  int rowInChunk = lane >> 3;
  int kOff = (lane & 7) * 8;

  const unsigned short* Abase = A + (size_t)m0 * Kd;
  const unsigned short* Bbase = Bt + (size_t)n0 * Kd;

  for (int k0 = 0; k0 < Kd; k0 += 64) {
    __syncthreads();
#pragma unroll
    for (int r = 0; r < 4; r++) {
      int c = wave * 4 + r;
      int row = c * 8 + rowInChunk;
      GLDS16(Abase + (size_t)row * Kd + k0 + kOff, ldsA + c * 512);
    }
#pragma unroll
    for (int r = 0; r < 4; r++) {
      int c = wave * 4 + r;
      int row = c * 8 + rowInChunk;
      GLDS16(Bbase + (size_t)row * Kd + k0 + kOff, ldsB + c * 512);
    }
    asm volatile("s_waitcnt vmcnt(0)" ::: "memory");
    __syncthreads();
#pragma unroll
    for (int kk = 0; kk < 2; kk++) {
      short8 af[4], bfr[4];
      int kb = kk * 32 + (lane >> 4) * 8;
#pragma unroll
      for (int i = 0; i < 4; i++) {
        int ar = wm + i * 16 + (lane & 15);
        af[i] = *(const short8*)(ldsA + ar * 64 + kb);
        int br = wn + i * 16 + (lane & 15);
        bfr[i] = *(const short8*)(ldsB + br * 64 + kb);
      }
#pragma unroll
      for (int i = 0; i < 4; i++)
#pragma unroll
        for (int j = 0; j < 4; j++)
          acc[i][j] = __builtin_amdgcn_mfma_f32_16x16x32_bf16(
              af[i], bfr[j], acc[i][j], 0, 0, 0);
    }
  }
  int cr = (lane >> 4) * 4;
  int cc = lane & 15;
#pragma unroll
  for (int i = 0; i < 4; i++)
#pragma unroll
    for (int j = 0; j < 4; j++)
#pragma unroll
      for (int rg = 0; rg < 4; rg++) {
        int row = m0 + wm + i * 16 + cr + rg;
        int col = n0 + wn + j * 16 + cc;
        if (BF16OUT)
          ((unsigned short*)Cv)[(size_t)row * N + col] = f2bf(acc[i][j][rg]);
        else
          ((float*)Cv)[(size_t)row * N + col] = acc[i][j][rg];
      }
}

// ------------------------------------------------- alpha/beta gate projection
__global__ __launch_bounds__(256) void fl_kernel(
    const float* __restrict__ x, const float* __restrict__ Wf,
    const float* __restrict__ bfv, const float* __restrict__ Wl,
    const float* __restrict__ blv, float* __restrict__ alpha,
    float* __restrict__ beta) {
  __shared__ float xs[1024];
  int m = blockIdx.x;
  int b = m >> 12, t = m & 4095;
  int tid = threadIdx.x;
  *(float4*)(xs + tid * 4) = *(const float4*)(x + (size_t)m * 1024 + tid * 4);
  __syncthreads();
  int out = tid >> 3, part = tid & 7;
  const float* W = (out < 16) ? Wf : Wl;
  int h = out & 15;
  float acc = 0.f;
  int k0 = part * 128;
#pragma unroll 4
  for (int kk = k0; kk < k0 + 128; kk++) acc = fmaf(xs[kk], W[kk * 16 + h], acc);
  acc += __shfl_xor(acc, 1);
  acc += __shfl_xor(acc, 2);
  acc += __shfl_xor(acc, 4);
  if (part == 0) {
    float bias = (out < 16) ? bfv[h] : blv[h];
    float z = acc + bias;
    float s = 1.f / (1.f + __expf(-z));
    float* dst = (out < 16) ? alpha : beta;
    dst[((size_t)(b * 16 + h)) * 4096 + t] = s;
  }
}

// ------------------------ conv + rmsnorm + low-rank mix + k-tilde normalize
__global__ __launch_bounds__(256) void prep_kernel(
    const unsigned short* __restrict__ xqkv, const unsigned short* __restrict__ rqk,
    const float* __restrict__ cq, const float* __restrict__ ck,
    const float* __restrict__ cv, const float* __restrict__ gs,
    const float* __restrict__ qnw, const float* __restrict__ knw,
    unsigned short* __restrict__ qt, unsigned short* __restrict__ kt,
    unsigned short* __restrict__ vc) {
  int m = blockIdx.x;
  int b = m >> 12, t = m & 4095;
  int tid = threadIdx.x;
  int c4 = tid << 2;
  int h = c4 >> 6;
  int j4 = c4 & 63;

  float wq[4][4], wk[4][4], wv[4][4];
#pragma unroll
  for (int u = 0; u < 4; u++) {
    *(float4*)wq[u] = *(const float4*)(cq + (c4 + u) * 4);
    *(float4*)wk[u] = *(const float4*)(ck + (c4 + u) * 4);
    *(float4*)wv[u] = *(const float4*)(cv + (c4 + u) * 4);
  }
  float qv[4] = {0, 0, 0, 0}, kv[4] = {0, 0, 0, 0}, vv[4] = {0, 0, 0, 0};
#pragma unroll
  for (int j = 0; j < 4; j++) {
    int tt = t + j - 3;
    if (tt < 0) continue;
    const unsigned short* xr = xqkv + ((size_t)((b << 12) + tt)) * 3072;
    ushort4 uq = *(const ushort4*)(xr + c4);
    ushort4 uk = *(const ushort4*)(xr + 1024 + c4);
    ushort4 uv = *(const ushort4*)(xr + 2048 + c4);
    float xq[4] = {bf2f(uq.x), bf2f(uq.y), bf2f(uq.z), bf2f(uq.w)};
    float xk[4] = {bf2f(uk.x), bf2f(uk.y), bf2f(uk.z), bf2f(uk.w)};
    float xv[4] = {bf2f(uv.x), bf2f(uv.y), bf2f(uv.z), bf2f(uv.w)};
#pragma unroll
    for (int u = 0; u < 4; u++) {
      qv[u] = fmaf(wq[u][j], xq[u], qv[u]);
      kv[u] = fmaf(wk[u][j], xk[u], kv[u]);
      vv[u] = fmaf(wv[u][j], xv[u], vv[u]);
    }
  }
  float ssq = qv[0] * qv[0] + qv[1] * qv[1] + qv[2] * qv[2] + qv[3] * qv[3];
  ssq += __shfl_xor(ssq, 1); ssq += __shfl_xor(ssq, 2);
  ssq += __shfl_xor(ssq, 4); ssq += __shfl_xor(ssq, 8);
  float qsc = rsqrtf(ssq * (1.f / 64.f) + 1e-6f);
  float ssk = kv[0] * kv[0] + kv[1] * kv[1] + kv[2] * kv[2] + kv[3] * kv[3];
  ssk += __shfl_xor(ssk, 1); ssk += __shfl_xor(ssk, 2);
  ssk += __shfl_xor(ssk, 4); ssk += __shfl_xor(ssk, 8);
  float ksc = rsqrtf(ssk * (1.f / 64.f) + 1e-6f);

  float lam = fabsf(gs[h]);
  float rq[4] = {0, 0, 0, 0}, rk[4] = {0, 0, 0, 0};
  if (j4 < R_) {
    const unsigned short* rr = rqk + (size_t)m * 1536;
    ushort4 uq = *(const ushort4*)(rr + h * R_ + j4);
    ushort4 uk = *(const ushort4*)(rr + 768 + h * R_ + j4);
    rq[0] = bf2f(uq.x); rq[1] = bf2f(uq.y); rq[2] = bf2f(uq.z); rq[3] = bf2f(uq.w);
    rk[0] = bf2f(uk.x); rk[1] = bf2f(uk.y); rk[2] = bf2f(uk.z); rk[3] = bf2f(uk.w);
  }
  float qtv[4], ksum[4];
#pragma unroll
  for (int u = 0; u < 4; u++) {
    float qn = qv[u] * qsc * qnw[j4 + u];
    float kn = kv[u] * ksc * knw[j4 + u];
    qtv[u] = fmaf(lam, rq[u], qn);
    ksum[u] = fmaf(lam, rk[u], kn);
  }
  float ss2 = ksum[0] * ksum[0] + ksum[1] * ksum[1] + ksum[2] * ksum[2] +
              ksum[3] * ksum[3];
  ss2 += __shfl_xor(ss2, 1); ss2 += __shfl_xor(ss2, 2);
  ss2 += __shfl_xor(ss2, 4); ss2 += __shfl_xor(ss2, 8);
  float inv = 1.f / fmaxf(sqrtf(ss2), 1e-12f);

  size_t ob = ((size_t)((b * 16 + h) * 4096 + t)) * 64 + j4;
  ushort4 oq, ok, ov;
  oq.x = f2bf(qtv[0]); oq.y = f2bf(qtv[1]); oq.z = f2bf(qtv[2]); oq.w = f2bf(qtv[3]);
  ok.x = f2bf(ksum[0] * inv); ok.y = f2bf(ksum[1] * inv);
  ok.z = f2bf(ksum[2] * inv); ok.w = f2bf(ksum[3] * inv);
  ov.x = f2bf(vv[0]); ov.y = f2bf(vv[1]); ov.z = f2bf(vv[2]); ov.w = f2bf(vv[3]);
  *(ushort4*)(qt + ob) = oq;
  *(ushort4*)(kt + ob) = ok;
  *(ushort4*)(vc + ob) = ov;
}

// -------------------------------------------------------- gated delta scan
// 8 blocks per (b,h): 1 wave each, rows rg*8..+7. Lane (r=l>>3, cg=l&7) owns
// mem[r][cg*8..+8]. Row reduce: 2 DPP adds + 1 ds_swizzle. Chunked LDS
// staging, double-buffered, reg prefetch in flight during compute.
__global__ __launch_bounds__(64) void scan_kernel(
    const unsigned short* __restrict__ qt, const unsigned short* __restrict__ kt,
    const unsigned short* __restrict__ vc, const float* __restrict__ al,
    const float* __restrict__ be, float* __restrict__ attn) {
  __shared__ alignas(16) float sk[2][CHUNK][64];
  __shared__ alignas(16) float sq[2][CHUNK][64];
  __shared__ alignas(16) float sv[2][CHUNK][8];
  __shared__ float sab[2][64];  // [buf][0..31]=alpha, [32..63]=beta

  int bid = blockIdx.x;       // 32 bh x 8 row-groups
  int bh = bid >> 3, rg = bid & 7;
  int b = bh >> 4, h = bh & 15;
  int r0 = rg * 8;
  int l = threadIdx.x;        // 0..63
  int r = r0 + (l >> 3);
  int cg = l & 7;

  const unsigned short* kb = kt + (size_t)bh * S_ * 64;
  const unsigned short* qb = qt + (size_t)bh * S_ * 64;
  const unsigned short* vb = vc + (size_t)bh * S_ * 64;
  const float* ap = al + (size_t)bh * S_;
  const float* bp = be + (size_t)bh * S_;
  float* op = attn + (size_t)(b * S_) * 1024 + h * 64 + r;

  float mem[8];
#pragma unroll
  for (int i = 0; i < 8; i++) mem[i] = 0.f;

  // prologue: chunk-0 loads into regs (k/q: 4 x short8; v: ushort4; ab: 1 f32)
  short8 rk[4], rq[4];
  ushort4 rv;
  float rab;
#pragma unroll
  for (int u = 0; u < 4; u++) {
    rk[u] = *(const short8*)(kb + u * 512 + l * 8);
    rq[u] = *(const short8*)(qb + u * 512 + l * 8);
  }
  rv = *(const ushort4*)(vb + (size_t)(l >> 1) * 64 + r0 + (l & 1) * 4);
  rab = (l < 32) ? ap[l] : bp[l - 32];

  const int nc = S_ / CHUNK;
  for (int c = 0; c < nc; ++c) {
    int p = c & 1;
    __syncthreads();
    {  // regs -> LDS buf p (convert bf16 -> f32)
      float* dk = &sk[p][0][0];
      float* dq = &sq[p][0][0];
#pragma unroll
      for (int u = 0; u < 4; u++) {
        f32x4 lo, hi;
#pragma unroll
        for (int j = 0; j < 4; j++) {
          lo[j] = bf2f((unsigned short)rk[u][j]);
          hi[j] = bf2f((unsigned short)rk[u][4 + j]);
        }
        *(f32x4*)(dk + u * 512 + l * 8) = lo;
        *(f32x4*)(dk + u * 512 + l * 8 + 4) = hi;
#pragma unroll
        for (int j = 0; j < 4; j++) {
          lo[j] = bf2f((unsigned short)rq[u][j]);
          hi[j] = bf2f((unsigned short)rq[u][4 + j]);
        }
        *(f32x4*)(dq + u * 512 + l * 8) = lo;
        *(f32x4*)(dq + u * 512 + l * 8 + 4) = hi;
      }
      float4 v4;
      v4.x = bf2f(rv.x); v4.y = bf2f(rv.y); v4.z = bf2f(rv.z); v4.w = bf2f(rv.w);
      *(float4*)&sv[p][l >> 1][(l & 1) * 4] = v4;
      sab[p][l] = rab;
    }
    if (c + 1 < nc) {  // issue next-chunk loads; in flight during compute
      size_t cb = (size_t)(c + 1) * 2048;
#pragma unroll
      for (int u = 0; u < 4; u++) {
        rk[u] = *(const short8*)(kb + cb + u * 512 + l * 8);
        rq[u] = *(const short8*)(qb + cb + u * 512 + l * 8);
      }
      int ct = (c + 1) * CHUNK;
      rv = *(const ushort4*)(vb + (size_t)(ct + (l >> 1)) * 64 + r0 + (l & 1) * 4);
      rab = (l < 32) ? ap[ct + l] : bp[ct + l - 32];
    }
    __syncthreads();
    int tg0 = c * CHUNK;
#pragma unroll 4
    for (int t = 0; t < CHUNK; t++) {
      f32x4 k0 = *(const f32x4*)&sk[p][t][cg * 8];
      f32x4 k1 = *(const f32x4*)&sk[p][t][cg * 8 + 4];
      f32x4 q0 = *(const f32x4*)&sq[p][t][cg * 8];
      f32x4 q1 = *(const f32x4*)&sq[p][t][cg * 8 + 4];
      float v = sv[p][t][l >> 3];
      float a = sab[p][t], bg = sab[p][CHUNK + t];

      float p01 = fmaf(mem[1], k0[1], mem[0] * k0[0]);
      float p23 = fmaf(mem[3], k0[3], mem[2] * k0[2]);
      float p45 = fmaf(mem[5], k1[1], mem[4] * k1[0]);
      float p67 = fmaf(mem[7], k1[3], mem[6] * k1[2]);
      float pp = rowsum8((p01 + p23) + (p45 + p67));

      float am[8];
#pragma unroll
      for (int i = 0; i < 8; i++) am[i] = a * mem[i];
      float bd = bg * (v - pp);
#pragma unroll
      for (int i = 0; i < 4; i++) {
        mem[i] = fmaf(bd, k0[i], am[i]);
        mem[4 + i] = fmaf(bd, k1[i], am[4 + i]);
      }
      float o01 = fmaf(mem[1], q0[1], mem[0] * q0[0]);
      float o23 = fmaf(mem[3], q0[3], mem[2] * q0[2]);
      float o45 = fmaf(mem[5], q1[1], mem[4] * q1[0]);
      float o67 = fmaf(mem[7], q1[3], mem[6] * q1[2]);
      float oo = rowsum8((o01 + o23) + (o45 + o67));
      if (cg == 0) op[(size_t)(tg0 + t) * 1024] = oo;
    }
  }
}

// ------------------------------------------------ output rmsnorm -> bf16 rows
__global__ __launch_bounds__(256) void rmsnorm_out_kernel(
    const float* __restrict__ attn, const float* __restrict__ onw,
    unsigned short* __restrict__ normed) {
  int m = blockIdx.x, tid = threadIdx.x;
  const float* row = attn + (size_t)m * 1024;
  float xv[4];
  *(float4*)xv = *(const float4*)(row + tid * 4);
  float ss = xv[0] * xv[0] + xv[1] * xv[1] + xv[2] * xv[2] + xv[3] * xv[3];
#pragma unroll
  for (int o = 1; o < 64; o <<= 1) ss += __shfl_xor(ss, o);
  __shared__ float wss[4];
  if ((tid & 63) == 0) wss[tid >> 6] = ss;
  __syncthreads();
  float tot = wss[0] + wss[1] + wss[2] + wss[3];
  float sc = rsqrtf(tot * (1.f / 1024.f) + 1e-6f);
  float wv[4];
  *(float4*)wv = *(const float4*)(onw + tid * 4);
  ushort4 o4;
  o4.x = f2bf(xv[0] * sc * wv[0]);
  o4.y = f2bf(xv[1] * sc * wv[1]);
  o4.z = f2bf(xv[2] * sc * wv[2]);
  o4.w = f2bf(xv[3] * sc * wv[3]);
  *(ushort4*)(normed + (size_t)m * 1024 + tid * 4) = o4;
}

// ---------------------------------------------------------------------------
extern "C" void kernel_launch(void* const* d_in, const int* in_sizes, int n_in,
                              void* d_out, int out_size, void* d_ws,
                              size_t ws_size, hipStream_t stream) {
  const float* x = (const float*)d_in[0];
  const float* Wq = (const float*)d_in[1];
  const float* Wk = (const float*)d_in[2];
  const float* Wv = (const float*)d_in[3];
  const float* Wo = (const float*)d_in[4];
  const float* conv_q = (const float*)d_in[5];
  const float* conv_k = (const float*)d_in[6];
  const float* conv_v = (const float*)d_in[7];
  const float* Wf = (const float*)d_in[8];
  const float* bfv = (const float*)d_in[9];
  const float* Wl = (const float*)d_in[10];
  const float* blv = (const float*)d_in[11];
  const float* gs = (const float*)d_in[14];
  const float* qn_w = (const float*)d_in[15];
  const float* kn_w = (const float*)d_in[16];
  const float* on_w = (const float*)d_in[17];

  char* ws = (char*)d_ws;
  size_t used = 0;
  auto alloc = [&](size_t bytes) -> void* {
    void* p = (void*)(ws + used);
    used += (bytes + 255) & ~(size_t)255;
    return p;
  };
  unsigned short* xb = (unsigned short*)alloc((size_t)M_ * D_ * 2);
  unsigned short* wqkv_t = (unsigned short*)alloc((size_t)3072 * 1024 * 2);
  unsigned short* wr_t = (unsigned short*)alloc((size_t)1536 * 1024 * 2);
  unsigned short* wo_t = (unsigned short*)alloc((size_t)1024 * 1024 * 2);
  unsigned short* xqkv = (unsigned short*)alloc((size_t)M_ * 3072 * 2);
  unsigned short* rqk = (unsigned short*)alloc((size_t)M_ * 1536 * 2);
  unsigned short* qt = (unsigned short*)alloc((size_t)M_ * 1024 * 2);
  unsigned short* kt = (unsigned short*)alloc((size_t)M_ * 1024 * 2);
  unsigned short* vc = (unsigned short*)alloc((size_t)M_ * 1024 * 2);
  float* alpha = (float*)alloc((size_t)B_ * H_ * S_ * 4);
  float* beta = (float*)alloc((size_t)B_ * H_ * S_ * 4);
  float* attn = (float*)xqkv;    // alias (xqkv dead after prep)
  unsigned short* normed = rqk;  // alias (rqk dead after prep)

  if (used > ws_size) return;

  cast_bf16_kernel<<<2048, 256, 0, stream>>>(x, xb, M_ * D_ / 4);

  dim3 tb(32, 8);
  transpose_w_kernel<<<dim3(32, 32), tb, 0, stream>>>(Wq, wqkv_t, 1024, 1024);
  transpose_w_kernel<<<dim3(32, 32), tb, 0, stream>>>(
      Wk, wqkv_t + (size_t)1024 * 1024, 1024, 1024);
  transpose_w_kernel<<<dim3(32, 32), tb, 0, stream>>>(
      Wv, wqkv_t + (size_t)2048 * 1024, 1024, 1024);
  transpose_w_kernel<<<dim3(24, 32), tb, 0, stream>>>(
      (const float*)d_in[12], wr_t, 1024, 768);
  transpose_w_kernel<<<dim3(24, 32), tb, 0, stream>>>(
      (const float*)d_in[13], wr_t + (size_t)768 * 1024, 1024, 768);
  transpose_w_kernel<<<dim3(32, 32), tb, 0, stream>>>(Wo, wo_t, 1024, 1024);

  gemm_bt_kernel<true><<<64 * 24, 256, 0, stream>>>(xb, wqkv_t, xqkv, M_, 3072, 1024);
  gemm_bt_kernel<true><<<64 * 12, 256, 0, stream>>>(xb, wr_t, rqk, M_, 1536, 1024);

  fl_kernel<<<M_, 256, 0, stream>>>(x, Wf, bfv, Wl, blv, alpha, beta);

  prep_kernel<<<M_, 256, 0, stream>>>(xqkv, rqk, conv_q, conv_k, conv_v, gs,
                                      qn_w, kn_w, qt, kt, vc);

  scan_kernel<<<B_ * H_ * 8, 64, 0, stream>>>(qt, kt, vc, alpha, beta, attn);

  rmsnorm_out_kernel<<<M_, 256, 0, stream>>>(attn, on_w, normed);

  gemm_bt_kernel<false><<<64 * 8, 256, 0, stream>>>(normed, wo_t, (float*)d_out,
                                                    M_, 1024, 1024);
}

// Round 5
// 895.280 us; speedup vs baseline: 2.1734x; 1.5943x over previous
//
#include <hip/hip_runtime.h>

// ---------------------------------------------------------------------------
// GDN attention block, MI355X (gfx950).
//   1. cast x -> bf16
//   2. transpose weights -> bf16 B^T packs (+ Wf|Wl pack)
//   3. bf16 MFMA GEMM (128x128 tile, global_load_lds w16), bf16 outputs
//   4. fl_gemm: alpha/beta = sigmoid(x@[Wf Wl]+b) via MFMA (M=8192,N=32)
//   5. prep: causal dwconv(K=4) + head rmsnorm + low-rank mix + k-tilde norm
//   6. scan: gated delta rule. 4 blocks/bh x 4 waves; wave = 4 rows x 16
//      lanes (4 chans). Row reduce = 4 pure-DPP adds (xor1,xor2,ror8,ror4) --
//      NO ds ops in the serial chain. Chunked double-buffered LDS staging,
//      reg prefetch in flight across barriers (T14). XCD-swizzled block map
//      so one bh's 4 blocks share an L2.
//   7. rmsnorm over D=1024 -> bf16
//   8. GEMM @ Wo -> d_out f32
// ---------------------------------------------------------------------------

typedef __attribute__((ext_vector_type(8))) short short8;
typedef __attribute__((ext_vector_type(4))) float f32x4;

#define B_ 2
#define S_ 4096
#define D_ 1024
#define H_ 16
#define R_ 48
#define M_ 8192  // B*S
#define CHUNK 32

__device__ __forceinline__ unsigned short f2bf(float f) {
  unsigned u = __float_as_uint(f);
  u += 0x7FFFu + ((u >> 16) & 1u);
  return (unsigned short)(u >> 16);
}
__device__ __forceinline__ float bf2f(unsigned short u) {
  return __uint_as_float(((unsigned)u) << 16);
}

template <int CTRL>
__device__ __forceinline__ float dppadd(float x) {
  return x + __int_as_float(__builtin_amdgcn_update_dpp(
                 0, __float_as_int(x), CTRL, 0xF, 0xF, true));
}
// sum across a 16-lane DPP row (our row-group): all lanes get the sum.
__device__ __forceinline__ float redrow16(float x) {
  x = dppadd<0xB1>(x);   // quad_perm [1,0,3,2]  (xor 1)
  x = dppadd<0x4E>(x);   // quad_perm [2,3,0,1]  (xor 2)
  x = dppadd<0x128>(x);  // row_ror:8
  x = dppadd<0x124>(x);  // row_ror:4
  return x;
}

#define GLDS16(g, l) __builtin_amdgcn_global_load_lds(                        \
    (const __attribute__((address_space(1))) unsigned int*)(g),              \
    (__attribute__((address_space(3))) unsigned int*)(l), 16, 0, 0)

// --------------------------------------------------------------- cast x->bf16
__global__ __launch_bounds__(256) void cast_bf16_kernel(
    const float* __restrict__ in, unsigned short* __restrict__ out, int n4) {
  int i = blockIdx.x * 256 + threadIdx.x;
  for (; i < n4; i += gridDim.x * 256) {
    float4 v = ((const float4*)in)[i];
    ushort4 o;
    o.x = f2bf(v.x); o.y = f2bf(v.y); o.z = f2bf(v.z); o.w = f2bf(v.w);
    ((ushort4*)out)[i] = o;
  }
}

// ------------------------------------------------- W[K][N] -> Wt[N][K] (bf16)
__global__ void transpose_w_kernel(const float* __restrict__ W,
                                   unsigned short* __restrict__ Wt,
                                   int Kd, int N) {
  __shared__ float tile[32][33];
  int n0 = blockIdx.x * 32, k0 = blockIdx.y * 32;
  int tx = threadIdx.x, ty = threadIdx.y;  // 32 x 8
#pragma unroll
  for (int i = 0; i < 32; i += 8)
    tile[ty + i][tx] = W[(size_t)(k0 + ty + i) * N + n0 + tx];
  __syncthreads();
#pragma unroll
  for (int i = 0; i < 32; i += 8)
    Wt[(size_t)(n0 + ty + i) * Kd + k0 + tx] = f2bf(tile[tx][ty + i]);
}

// -------------------------------------- pack [Wf|Wl] -> wfl[32][1024] bf16
__global__ __launch_bounds__(256) void pack_wfl_kernel(
    const float* __restrict__ Wf, const float* __restrict__ Wl,
    unsigned short* __restrict__ wfl) {
  int o = blockIdx.x * 256 + threadIdx.x;  // 32768 total
  int j = o >> 10, k = o & 1023;
  float v = (j < 16) ? Wf[k * 16 + j] : Wl[k * 16 + (j - 16)];
  wfl[o] = f2bf(v);
}

// ------------------------------------------------------------- bf16 MFMA GEMM
template <bool BF16OUT>
__global__ __launch_bounds__(256) void gemm_bt_kernel(
    const unsigned short* __restrict__ A, const unsigned short* __restrict__ Bt,
    void* __restrict__ Cv, int M, int N, int Kd) {
  __shared__ alignas(16) unsigned short lds[2 * 128 * 64];  // 32 KiB
  unsigned short* ldsA = lds;
  unsigned short* ldsB = lds + 128 * 64;
  int tid = threadIdx.x;
  int wave = tid >> 6, lane = tid & 63;
  int nBlocks = N >> 7;
  int bm = blockIdx.x / nBlocks, bn = blockIdx.x % nBlocks;
  int m0 = bm << 7, n0 = bn << 7;
  int wm = (wave >> 1) << 6, wn = (wave & 1) << 6;

  f32x4 acc[4][4] = {};

  int rowInChunk = lane >> 3;
  int kOff = (lane & 7) * 8;

  const unsigned short* Abase = A + (size_t)m0 * Kd;
  const unsigned short* Bbase = Bt + (size_t)n0 * Kd;

  for (int k0 = 0; k0 < Kd; k0 += 64) {
    __syncthreads();
#pragma unroll
    for (int r = 0; r < 4; r++) {
      int c = wave * 4 + r;
      int row = c * 8 + rowInChunk;
      GLDS16(Abase + (size_t)row * Kd + k0 + kOff, ldsA + c * 512);
    }
#pragma unroll
    for (int r = 0; r < 4; r++) {
      int c = wave * 4 + r;
      int row = c * 8 + rowInChunk;
      GLDS16(Bbase + (size_t)row * Kd + k0 + kOff, ldsB + c * 512);
    }
    asm volatile("s_waitcnt vmcnt(0)" ::: "memory");
    __syncthreads();
#pragma unroll
    for (int kk = 0; kk < 2; kk++) {
      short8 af[4], bfr[4];
      int kb = kk * 32 + (lane >> 4) * 8;
#pragma unroll
      for (int i = 0; i < 4; i++) {
        int ar = wm + i * 16 + (lane & 15);
        af[i] = *(const short8*)(ldsA + ar * 64 + kb);
        int br = wn + i * 16 + (lane & 15);
        bfr[i] = *(const short8*)(ldsB + br * 64 + kb);
      }
#pragma unroll
      for (int i = 0; i < 4; i++)
#pragma unroll
        for (int j = 0; j < 4; j++)
          acc[i][j] = __builtin_amdgcn_mfma_f32_16x16x32_bf16(
              af[i], bfr[j], acc[i][j], 0, 0, 0);
    }
  }
  int cr = (lane >> 4) * 4;
  int cc = lane & 15;
#pragma unroll
  for (int i = 0; i < 4; i++)
#pragma unroll
    for (int j = 0; j < 4; j++)
#pragma unroll
      for (int rg = 0; rg < 4; rg++) {
        int row = m0 + wm + i * 16 + cr + rg;
        int col = n0 + wn + j * 16 + cc;
        if (BF16OUT)
          ((unsigned short*)Cv)[(size_t)row * N + col] = f2bf(acc[i][j][rg]);
        else
          ((float*)Cv)[(size_t)row * N + col] = acc[i][j][rg];
      }
}

// ---------------------------- alpha/beta via MFMA: [8192x1024]@[32x1024]^T
__global__ __launch_bounds__(256) void fl_gemm_kernel(
    const unsigned short* __restrict__ xb, const unsigned short* __restrict__ wfl,
    const float* __restrict__ bfv, const float* __restrict__ blv,
    float* __restrict__ alpha, float* __restrict__ beta) {
  __shared__ alignas(16) unsigned short ldsA[128 * 64];
  __shared__ alignas(16) unsigned short ldsB[32 * 64];
  int tid = threadIdx.x, wave = tid >> 6, lane = tid & 63;
  int m0 = blockIdx.x << 7;
  f32x4 acc[2][2] = {};
  int rowInChunk = lane >> 3, kOff = (lane & 7) * 8;
  const unsigned short* Abase = xb + (size_t)m0 * 1024;

  for (int k0 = 0; k0 < 1024; k0 += 64) {
    __syncthreads();
#pragma unroll
    for (int r = 0; r < 4; r++) {
      int ch = wave * 4 + r;
      int row = ch * 8 + rowInChunk;
      GLDS16(Abase + (size_t)row * 1024 + k0 + kOff, ldsA + ch * 512);
    }
    {
      int row = wave * 8 + rowInChunk;
      GLDS16(wfl + (size_t)row * 1024 + k0 + kOff, ldsB + wave * 512);
    }
    asm volatile("s_waitcnt vmcnt(0)" ::: "memory");
    __syncthreads();
#pragma unroll
    for (int kk = 0; kk < 2; kk++) {
      int kb2 = kk * 32 + (lane >> 4) * 8;
      short8 af[2], bfr[2];
#pragma unroll
      for (int i = 0; i < 2; i++)
        af[i] = *(const short8*)(ldsA + (wave * 32 + i * 16 + (lane & 15)) * 64 + kb2);
#pragma unroll
      for (int j = 0; j < 2; j++)
        bfr[j] = *(const short8*)(ldsB + (j * 16 + (lane & 15)) * 64 + kb2);
#pragma unroll
      for (int i = 0; i < 2; i++)
#pragma unroll
        for (int j = 0; j < 2; j++)
          acc[i][j] = __builtin_amdgcn_mfma_f32_16x16x32_bf16(
              af[i], bfr[j], acc[i][j], 0, 0, 0);
    }
  }
  int cr = (lane >> 4) * 4, cc = lane & 15;
#pragma unroll
  for (int i = 0; i < 2; i++)
#pragma unroll
    for (int j = 0; j < 2; j++)
#pragma unroll
      for (int rg = 0; rg < 4; rg++) {
        int row = m0 + wave * 32 + i * 16 + cr + rg;
        int col = j * 16 + cc;
        float z = acc[i][j][rg] + ((col < 16) ? bfv[col] : blv[col - 16]);
        float s = 1.f / (1.f + __expf(-z));
        int bb = row >> 12, tt = row & 4095, hh = col & 15;
        float* dst = (col < 16) ? alpha : beta;
        dst[((size_t)(bb * 16 + hh)) * 4096 + tt] = s;
      }
}

// ------------------------ conv + rmsnorm + low-rank mix + k-tilde normalize
__global__ __launch_bounds__(256) void prep_kernel(
    const unsigned short* __restrict__ xqkv, const unsigned short* __restrict__ rqk,
    const float* __restrict__ cq, const float* __restrict__ ck,
    const float* __restrict__ cv, const float* __restrict__ gs,
    const float* __restrict__ qnw, const float* __restrict__ knw,
    unsigned short* __restrict__ qt, unsigned short* __restrict__ kt,
    unsigned short* __restrict__ vc) {
  int m = blockIdx.x;
  int b = m >> 12, t = m & 4095;
  int tid = threadIdx.x;
  int c4 = tid << 2;
  int h = c4 >> 6;
  int j4 = c4 & 63;

  float wq[4][4], wk[4][4], wv[4][4];
#pragma unroll
  for (int u = 0; u < 4; u++) {
    *(float4*)wq[u] = *(const float4*)(cq + (c4 + u) * 4);
    *(float4*)wk[u] = *(const float4*)(ck + (c4 + u) * 4);
    *(float4*)wv[u] = *(const float4*)(cv + (c4 + u) * 4);
  }
  float qv[4] = {0, 0, 0, 0}, kv[4] = {0, 0, 0, 0}, vv[4] = {0, 0, 0, 0};
#pragma unroll
  for (int j = 0; j < 4; j++) {
    int tt = t + j - 3;
    if (tt < 0) continue;
    const unsigned short* xr = xqkv + ((size_t)((b << 12) + tt)) * 3072;
    ushort4 uq = *(const ushort4*)(xr + c4);
    ushort4 uk = *(const ushort4*)(xr + 1024 + c4);
    ushort4 uv = *(const ushort4*)(xr + 2048 + c4);
    float xq[4] = {bf2f(uq.x), bf2f(uq.y), bf2f(uq.z), bf2f(uq.w)};
    float xk[4] = {bf2f(uk.x), bf2f(uk.y), bf2f(uk.z), bf2f(uk.w)};
    float xv[4] = {bf2f(uv.x), bf2f(uv.y), bf2f(uv.z), bf2f(uv.w)};
#pragma unroll
    for (int u = 0; u < 4; u++) {
      qv[u] = fmaf(wq[u][j], xq[u], qv[u]);
      kv[u] = fmaf(wk[u][j], xk[u], kv[u]);
      vv[u] = fmaf(wv[u][j], xv[u], vv[u]);
    }
  }
  float ssq = qv[0] * qv[0] + qv[1] * qv[1] + qv[2] * qv[2] + qv[3] * qv[3];
  ssq += __shfl_xor(ssq, 1); ssq += __shfl_xor(ssq, 2);
  ssq += __shfl_xor(ssq, 4); ssq += __shfl_xor(ssq, 8);
  float qsc = rsqrtf(ssq * (1.f / 64.f) + 1e-6f);
  float ssk = kv[0] * kv[0] + kv[1] * kv[1] + kv[2] * kv[2] + kv[3] * kv[3];
  ssk += __shfl_xor(ssk, 1); ssk += __shfl_xor(ssk, 2);
  ssk += __shfl_xor(ssk, 4); ssk += __shfl_xor(ssk, 8);
  float ksc = rsqrtf(ssk * (1.f / 64.f) + 1e-6f);

  float lam = fabsf(gs[h]);
  float rq[4] = {0, 0, 0, 0}, rk[4] = {0, 0, 0, 0};
  if (j4 < R_) {
    const unsigned short* rr = rqk + (size_t)m * 1536;
    ushort4 uq = *(const ushort4*)(rr + h * R_ + j4);
    ushort4 uk = *(const ushort4*)(rr + 768 + h * R_ + j4);
    rq[0] = bf2f(uq.x); rq[1] = bf2f(uq.y); rq[2] = bf2f(uq.z); rq[3] = bf2f(uq.w);
    rk[0] = bf2f(uk.x); rk[1] = bf2f(uk.y); rk[2] = bf2f(uk.z); rk[3] = bf2f(uk.w);
  }
  float qtv[4], ksum[4];
#pragma unroll
  for (int u = 0; u < 4; u++) {
    float qn = qv[u] * qsc * qnw[j4 + u];
    float kn = kv[u] * ksc * knw[j4 + u];
    qtv[u] = fmaf(lam, rq[u], qn);
    ksum[u] = fmaf(lam, rk[u], kn);
  }
  float ss2 = ksum[0] * ksum[0] + ksum[1] * ksum[1] + ksum[2] * ksum[2] +
              ksum[3] * ksum[3];
  ss2 += __shfl_xor(ss2, 1); ss2 += __shfl_xor(ss2, 2);
  ss2 += __shfl_xor(ss2, 4); ss2 += __shfl_xor(ss2, 8);
  float inv = 1.f / fmaxf(sqrtf(ss2), 1e-12f);

  size_t ob = ((size_t)((b * 16 + h) * 4096 + t)) * 64 + j4;
  ushort4 oq, ok, ov;
  oq.x = f2bf(qtv[0]); oq.y = f2bf(qtv[1]); oq.z = f2bf(qtv[2]); oq.w = f2bf(qtv[3]);
  ok.x = f2bf(ksum[0] * inv); ok.y = f2bf(ksum[1] * inv);
  ok.z = f2bf(ksum[2] * inv); ok.w = f2bf(ksum[3] * inv);
  ov.x = f2bf(vv[0]); ov.y = f2bf(vv[1]); ov.z = f2bf(vv[2]); ov.w = f2bf(vv[3]);
  *(ushort4*)(qt + ob) = oq;
  *(ushort4*)(kt + ob) = ok;
  *(ushort4*)(vc + ob) = ov;
}

// -------------------------------------------------------- gated delta scan
// 128 blocks (XCD-swizzled), 4 blocks per bh, 4 waves per block.
// Wave = 4 rows x 16 lanes, 4 chans/lane. Reduce = 4 pure-DPP adds.
__global__ __launch_bounds__(256) void scan_kernel(
    const unsigned short* __restrict__ qt, const unsigned short* __restrict__ kt,
    const unsigned short* __restrict__ vc, const float* __restrict__ al,
    const float* __restrict__ be, float* __restrict__ attn) {
  __shared__ alignas(16) float sk[2][CHUNK][64];
  __shared__ alignas(16) float sq[2][CHUNK][64];
  __shared__ alignas(16) float sv[2][CHUNK][16];
  __shared__ float sab[2][2][CHUNK];

  int i = blockIdx.x;
  int bh = (i & 7) * 4 + ((i >> 3) & 3);  // same-bh blocks share an XCD
  int grp = i >> 5;                       // 0..3 -> rows grp*16..+15
  int b = bh >> 4, h = bh & 15;
  int tid = threadIdx.x;
  int wave = tid >> 6, l = tid & 63;
  int rw = l >> 4;    // row in wave
  int li = l & 15;    // lane in DPP row
  int r = grp * 16 + wave * 4 + rw;
  int c = li * 4;
  int vr = wave * 4 + rw;

  const unsigned short* kb = kt + (size_t)bh * S_ * 64;
  const unsigned short* qb = qt + (size_t)bh * S_ * 64;
  const unsigned short* vb = vc + (size_t)bh * S_ * 64 + grp * 16;
  const float* ap = al + (size_t)bh * S_;
  const float* bp = be + (size_t)bh * S_;
  float* op = attn + (size_t)(b * S_) * 1024 + h * 64 + r;

  float mem[4] = {0.f, 0.f, 0.f, 0.f};

  // prefetch chunk 0 into regs
  short8 rk = *(const short8*)(kb + tid * 8);
  short8 rq = *(const short8*)(qb + tid * 8);
  ushort4 rv;
  float rab = 0.f;
  if (tid < 128)
    rv = *(const ushort4*)(vb + (size_t)(tid >> 2) * 64 + (tid & 3) * 4);
  if (tid >= 128 && tid < 192) {
    int t2 = tid - 128;
    rab = (t2 < 32) ? ap[t2] : bp[t2 - 32];
  }

  const int nc = S_ / CHUNK;
  for (int cch = 0; cch < nc; ++cch) {
    int p = cch & 1;
    __syncthreads();
    {  // regs -> LDS (bf16 -> f32)
      int t = tid >> 3, ch = (tid & 7) * 8;
      f32x4 lo, hi;
#pragma unroll
      for (int j = 0; j < 4; j++) {
        lo[j] = bf2f((unsigned short)rk[j]);
        hi[j] = bf2f((unsigned short)rk[4 + j]);
      }
      *(f32x4*)&sk[p][t][ch] = lo;
      *(f32x4*)&sk[p][t][ch + 4] = hi;
#pragma unroll
      for (int j = 0; j < 4; j++) {
        lo[j] = bf2f((unsigned short)rq[j]);
        hi[j] = bf2f((unsigned short)rq[4 + j]);
      }
      *(f32x4*)&sq[p][t][ch] = lo;
      *(f32x4*)&sq[p][t][ch + 4] = hi;
      if (tid < 128) {
        float4 v4;
        v4.x = bf2f(rv.x); v4.y = bf2f(rv.y); v4.z = bf2f(rv.z); v4.w = bf2f(rv.w);
        *(float4*)&sv[p][tid >> 2][(tid & 3) * 4] = v4;
      }
      if (tid >= 128 && tid < 192) {
        int t2 = tid - 128;
        sab[p][t2 >> 5][t2 & 31] = rab;
      }
    }
    if (cch + 1 < nc) {  // issue next-chunk loads; in flight during compute
      size_t cb = (size_t)(cch + 1) * (CHUNK * 64);
      rk = *(const short8*)(kb + cb + tid * 8);
      rq = *(const short8*)(qb + cb + tid * 8);
      if (tid < 128)
        rv = *(const ushort4*)(vb + cb + (size_t)(tid >> 2) * 64 + (tid & 3) * 4);
      if (tid >= 128 && tid < 192) {
        int t2 = tid - 128;
        int ct = (cch + 1) * CHUNK;
        rab = (t2 < 32) ? ap[ct + t2] : bp[ct + t2 - 32];
      }
    }
    __syncthreads();
    int tg0 = cch * CHUNK;
#pragma unroll 4
    for (int t = 0; t < CHUNK; t++) {
      f32x4 kf = *(const f32x4*)&sk[p][t][c];
      f32x4 qf = *(const f32x4*)&sq[p][t][c];
      float v = sv[p][t][vr];
      float a = sab[p][0][t], bg = sab[p][1][t];

      float pa = fmaf(mem[1], kf[1], mem[0] * kf[0]);
      float pb = fmaf(mem[3], kf[3], mem[2] * kf[2]);
      float pp = redrow16(pa + pb);
      float bd = bg * (v - pp);
#pragma unroll
      for (int u = 0; u < 4; u++) mem[u] = fmaf(bd, kf[u], a * mem[u]);
      float oa = fmaf(mem[1], qf[1], mem[0] * qf[0]);
      float ob = fmaf(mem[3], qf[3], mem[2] * qf[2]);
      float oo = redrow16(oa + ob);
      if (li == 0) op[(size_t)(tg0 + t) * 1024] = oo;
    }
  }
}

// ------------------------------------------------ output rmsnorm -> bf16 rows
__global__ __launch_bounds__(256) void rmsnorm_out_kernel(
    const float* __restrict__ attn, const float* __restrict__ onw,
    unsigned short* __restrict__ normed) {
  int m = blockIdx.x, tid = threadIdx.x;
  const float* row = attn + (size_t)m * 1024;
  float xv[4];
  *(float4*)xv = *(const float4*)(row + tid * 4);
  float ss = xv[0] * xv[0] + xv[1] * xv[1] + xv[2] * xv[2] + xv[3] * xv[3];
#pragma unroll
  for (int o = 1; o < 64; o <<= 1) ss += __shfl_xor(ss, o);
  __shared__ float wss[4];
  if ((tid & 63) == 0) wss[tid >> 6] = ss;
  __syncthreads();
  float tot = wss[0] + wss[1] + wss[2] + wss[3];
  float sc = rsqrtf(tot * (1.f / 1024.f) + 1e-6f);
  float wv[4];
  *(float4*)wv = *(const float4*)(onw + tid * 4);
  ushort4 o4;
  o4.x = f2bf(xv[0] * sc * wv[0]);
  o4.y = f2bf(xv[1] * sc * wv[1]);
  o4.z = f2bf(xv[2] * sc * wv[2]);
  o4.w = f2bf(xv[3] * sc * wv[3]);
  *(ushort4*)(normed + (size_t)m * 1024 + tid * 4) = o4;
}

// ---------------------------------------------------------------------------
extern "C" void kernel_launch(void* const* d_in, const int* in_sizes, int n_in,
                              void* d_out, int out_size, void* d_ws,
                              size_t ws_size, hipStream_t stream) {
  const float* x = (const float*)d_in[0];
  const float* Wq = (const float*)d_in[1];
  const float* Wk = (const float*)d_in[2];
  const float* Wv = (const float*)d_in[3];
  const float* Wo = (const float*)d_in[4];
  const float* conv_q = (const float*)d_in[5];
  const float* conv_k = (const float*)d_in[6];
  const float* conv_v = (const float*)d_in[7];
  const float* Wf = (const float*)d_in[8];
  const float* bfv = (const float*)d_in[9];
  const float* Wl = (const float*)d_in[10];
  const float* blv = (const float*)d_in[11];
  const float* gs = (const float*)d_in[14];
  const float* qn_w = (const float*)d_in[15];
  const float* kn_w = (const float*)d_in[16];
  const float* on_w = (const float*)d_in[17];

  char* ws = (char*)d_ws;
  size_t used = 0;
  auto alloc = [&](size_t bytes) -> void* {
    void* p = (void*)(ws + used);
    used += (bytes + 255) & ~(size_t)255;
    return p;
  };
  unsigned short* xb = (unsigned short*)alloc((size_t)M_ * D_ * 2);
  unsigned short* wqkv_t = (unsigned short*)alloc((size_t)3072 * 1024 * 2);
  unsigned short* wr_t = (unsigned short*)alloc((size_t)1536 * 1024 * 2);
  unsigned short* wo_t = (unsigned short*)alloc((size_t)1024 * 1024 * 2);
  unsigned short* wfl = (unsigned short*)alloc((size_t)32 * 1024 * 2);
  unsigned short* xqkv = (unsigned short*)alloc((size_t)M_ * 3072 * 2);
  unsigned short* rqk = (unsigned short*)alloc((size_t)M_ * 1536 * 2);
  unsigned short* qt = (unsigned short*)alloc((size_t)M_ * 1024 * 2);
  unsigned short* kt = (unsigned short*)alloc((size_t)M_ * 1024 * 2);
  unsigned short* vc = (unsigned short*)alloc((size_t)M_ * 1024 * 2);
  float* alpha = (float*)alloc((size_t)B_ * H_ * S_ * 4);
  float* beta = (float*)alloc((size_t)B_ * H_ * S_ * 4);
  float* attn = (float*)xqkv;    // alias (xqkv dead after prep)
  unsigned short* normed = rqk;  // alias (rqk dead after prep)

  if (used > ws_size) return;

  cast_bf16_kernel<<<2048, 256, 0, stream>>>(x, xb, M_ * D_ / 4);

  dim3 tb(32, 8);
  transpose_w_kernel<<<dim3(32, 32), tb, 0, stream>>>(Wq, wqkv_t, 1024, 1024);
  transpose_w_kernel<<<dim3(32, 32), tb, 0, stream>>>(
      Wk, wqkv_t + (size_t)1024 * 1024, 1024, 1024);
  transpose_w_kernel<<<dim3(32, 32), tb, 0, stream>>>(
      Wv, wqkv_t + (size_t)2048 * 1024, 1024, 1024);
  transpose_w_kernel<<<dim3(24, 32), tb, 0, stream>>>(
      (const float*)d_in[12], wr_t, 1024, 768);
  transpose_w_kernel<<<dim3(24, 32), tb, 0, stream>>>(
      (const float*)d_in[13], wr_t + (size_t)768 * 1024, 1024, 768);
  transpose_w_kernel<<<dim3(32, 32), tb, 0, stream>>>(Wo, wo_t, 1024, 1024);
  pack_wfl_kernel<<<128, 256, 0, stream>>>(Wf, Wl, wfl);

  gemm_bt_kernel<true><<<64 * 24, 256, 0, stream>>>(xb, wqkv_t, xqkv, M_, 3072, 1024);
  gemm_bt_kernel<true><<<64 * 12, 256, 0, stream>>>(xb, wr_t, rqk, M_, 1536, 1024);

  fl_gemm_kernel<<<64, 256, 0, stream>>>(xb, wfl, bfv, blv, alpha, beta);

  prep_kernel<<<M_, 256, 0, stream>>>(xqkv, rqk, conv_q, conv_k, conv_v, gs,
                                      qn_w, kn_w, qt, kt, vc);

  scan_kernel<<<128, 256, 0, stream>>>(qt, kt, vc, alpha, beta, attn);

  rmsnorm_out_kernel<<<M_, 256, 0, stream>>>(attn, on_w, normed);

  gemm_bt_kernel<false><<<64 * 8, 256, 0, stream>>>(normed, wo_t, (float*)d_out,
                                                    M_, 1024, 1024);
}